// Round 1
// baseline (1549.591 us; speedup 1.0000x reference)
//
#include <hip/hip_runtime.h>

#define NB 64
#define ND 128
#define NT 2048
#define NK 1024
#define NN (NB*NT)            // 131072
#define DTSTRIDE (ND*NT)      // 262144, b-stride in x

// ---- workspace layout (float index) ----
#define WS_ET    0            // 131072 floats, ET[d][k] transposed embeddings
#define WS_SSX   131072       // 131072 floats, |x_n|^2
#define WS_SSE   262144       // 1024 floats,  |e_k|^2
#define WS_DW    263168       // 131072 floats, scatter-sum dw[k][d]
#define WS_CS    394240       // 1024 floats, laplace-smoothed cluster size
#define WS_CNT   395264       // 1024 ints, counts
#define WS_IDX   396288       // 131072 ints, argmin indices
#define WS_LOSS  527360       // 1 float, sum of best distances
// total ~2.06 MB

// ---- output layout (concatenated, all fp32) ----
#define O_OUT 0
#define O_LC  16777216
#define O_LV  16777217
#define O_IDX 16777218
#define O_NE  16908290        // O_IDX + 131072

// Kernel 1: transpose embeddings [K][D] -> ET [D][K], and |e_k|^2.
__global__ void prep_e(const float* __restrict__ emb, float* __restrict__ ET,
                       float* __restrict__ sse) {
    int tid = threadIdx.x;
    int k   = blockIdx.x * 16 + (tid >> 4);
    int l   = tid & 15;
    float ss = 0.f;
    #pragma unroll
    for (int it = 0; it < 2; ++it) {
        int d0 = l * 4 + it * 64;
        float4 v = *(const float4*)(emb + k * ND + d0);
        ET[(d0+0)*NK + k] = v.x;
        ET[(d0+1)*NK + k] = v.y;
        ET[(d0+2)*NK + k] = v.z;
        ET[(d0+3)*NK + k] = v.w;
        ss = fmaf(v.x, v.x, ss); ss = fmaf(v.y, v.y, ss);
        ss = fmaf(v.z, v.z, ss); ss = fmaf(v.w, v.w, ss);
    }
    // reduce across the 16 lanes sharing k
    for (int m = 1; m <= 8; m <<= 1) ss += __shfl_xor(ss, m);
    if (l == 0) sse[k] = ss;
}

// Kernel 2: |x_n|^2 (coalesced along t).
__global__ void calc_ssx(const float* __restrict__ x, float* __restrict__ ssx) {
    int b = blockIdx.x >> 3;
    int t = ((blockIdx.x & 7) << 8) + threadIdx.x;
    const float* xp = x + b * DTSTRIDE + t;
    float ss = 0.f;
    #pragma unroll 8
    for (int d = 0; d < ND; ++d) { float v = xp[d * NT]; ss = fmaf(v, v, ss); }
    ssx[b * NT + t] = ss;
}

// Kernel 3: fused distance GEMM + argmin + counts + loss-sum.
// Tile: 128 n x 128 k per WG; 8x8 per thread; D staged in two 64-deep chunks.
__launch_bounds__(256, 2)
__global__ void gemm_argmin(const float* __restrict__ x, const float* __restrict__ ET,
                            const float* __restrict__ ssx, const float* __restrict__ sse,
                            float* __restrict__ out, int* __restrict__ idxi,
                            int* __restrict__ counts, float* __restrict__ loss) {
    __shared__ float xs[64][128];   // 32 KB  xs[dd][n_local]
    __shared__ float es[64][128];   // 32 KB  es[dd][k_local]
    int tid = threadIdx.x;
    int blk = blockIdx.x;
    int b   = blk >> 4;
    int t0  = (blk & 15) << 7;
    int n0  = b * NT + t0;
    int tx  = tid & 15, ty = tid >> 4;
    int tx8 = tx * 8,   ty8 = ty * 8;
    int c4  = (tid & 31) * 4;       // staging column (x4)
    int r0  = tid >> 5;             // staging row base

    float bestD[8]; int bestK[8]; float ssxv[8];
    #pragma unroll
    for (int i = 0; i < 8; ++i) {
        bestD[i] = 3.4e38f; bestK[i] = 0;
        ssxv[i]  = ssx[n0 + ty8 + i];
    }

    for (int kt = 0; kt < 8; ++kt) {
        float p[8][8];
        #pragma unroll
        for (int i = 0; i < 8; ++i)
            #pragma unroll
            for (int j = 0; j < 8; ++j) p[i][j] = 0.f;

        for (int dc = 0; dc < 2; ++dc) {
            __syncthreads();
            int d0 = dc * 64;
            #pragma unroll
            for (int r = 0; r < 8; ++r) {
                int dd = r0 + r * 8;
                *(float4*)(&xs[dd][c4]) = *(const float4*)(x  + b*DTSTRIDE + (d0+dd)*NT + t0 + c4);
                *(float4*)(&es[dd][c4]) = *(const float4*)(ET + (d0+dd)*NK + (kt<<7) + c4);
            }
            __syncthreads();
            #pragma unroll 2
            for (int dd = 0; dd < 64; ++dd) {
                float4 xa = *(float4*)&xs[dd][ty8];
                float4 xb = *(float4*)&xs[dd][ty8+4];
                float4 ea = *(float4*)&es[dd][tx8];
                float4 eb = *(float4*)&es[dd][tx8+4];
                float xr[8] = {xa.x,xa.y,xa.z,xa.w,xb.x,xb.y,xb.z,xb.w};
                float er[8] = {ea.x,ea.y,ea.z,ea.w,eb.x,eb.y,eb.z,eb.w};
                #pragma unroll
                for (int i = 0; i < 8; ++i)
                    #pragma unroll
                    for (int j = 0; j < 8; ++j)
                        p[i][j] = fmaf(xr[i], er[j], p[i][j]);
            }
        }
        // dist = (|x|^2 + |e|^2) - 2p ; merge ascending k with strict < (first-min tiebreak)
        #pragma unroll
        for (int j = 0; j < 8; ++j) {
            int   kidx = (kt << 7) + tx8 + j;
            float ssev = sse[kidx];
            #pragma unroll
            for (int i = 0; i < 8; ++i) {
                float t1   = ssxv[i] + ssev;
                float dist = fmaf(-2.f, p[i][j], t1);
                if (dist < bestD[i]) { bestD[i] = dist; bestK[i] = kidx; }
            }
        }
    }
    // cross-lane argmin over the 16 tx lanes (ties -> smaller k)
    #pragma unroll
    for (int i = 0; i < 8; ++i) {
        float d = bestD[i]; int kk = bestK[i];
        for (int m = 1; m <= 8; m <<= 1) {
            float od = __shfl_xor(d, m);
            int   ok = __shfl_xor(kk, m);
            if (od < d || (od == d && ok < kk)) { d = od; kk = ok; }
        }
        bestD[i] = d; bestK[i] = kk;
    }
    if (tx == 0) {
        float ls = 0.f;
        #pragma unroll
        for (int i = 0; i < 8; ++i) {
            int n = n0 + ty8 + i;
            out[O_IDX + n] = (float)bestK[i];
            idxi[n] = bestK[i];
            atomicAdd(&counts[bestK[i]], 1);
            ls += bestD[i];
        }
        atomicAdd(loss, ls);
    }
}

// Kernel 4: gather quantized -> out (straight-through value) + scatter dw.
__global__ void scatter_out_dw(const float* __restrict__ x, const float* __restrict__ ET,
                               const int* __restrict__ idxi, float* __restrict__ out,
                               float* __restrict__ dw) {
    int b = blockIdx.x >> 3;
    int t = ((blockIdx.x & 7) << 8) + threadIdx.x;
    int k = idxi[b * NT + t];
    const float* xp = x + b * DTSTRIDE + t;
    float*       op = out + O_OUT + b * DTSTRIDE + t;
    #pragma unroll 4
    for (int d = 0; d < ND; ++d) {
        float xv = xp[d * NT];
        float q  = ET[d * NK + k];
        op[d * NT] = xv + (q - xv);      // replicate x + (q - x) rounding
        atomicAdd(&dw[k * ND + d], xv);
    }
}

// Kernel 5: cluster-size path (n, cs) + loss scalars. One WG.
__global__ void cs_loss(const int* __restrict__ counts, const float* __restrict__ ch,
                        const float* __restrict__ loss, float* __restrict__ csv,
                        float* __restrict__ out) {
    __shared__ float red[256];
    int tid = threadIdx.x;
    const float DECF = (float)(1.0 - 0.99);   // matches jnp fp32 of (1-DECAY)
    float s = 0.f;
    #pragma unroll
    for (int r = 0; r < 4; ++r) {
        int k = tid + r * 256;
        float c = (float)counts[k];
        float e = ch[k];
        float hid = e - (e - c) * DECF;
        s += hid / DECF;
    }
    red[tid] = s; __syncthreads();
    for (int off = 128; off > 0; off >>= 1) {
        if (tid < off) red[tid] += red[tid + off];
        __syncthreads();
    }
    float n = red[0];
    const float KEPSF = (float)(1024.0 * 1e-5);
    #pragma unroll
    for (int r = 0; r < 4; ++r) {
        int k = tid + r * 256;
        float c = (float)counts[k];
        float e = ch[k];
        float hid = e - (e - c) * DECF;
        float a = hid / DECF;
        csv[k] = (a + 1e-5f) / (n + KEPSF) * n;
    }
    if (tid == 0) {
        float mean = loss[0] / 16777216.f;
        out[O_LC] = 0.25f * mean;
        out[O_LV] = mean;
    }
}

// Kernel 6: new_embeddings = ((ema_dw EMA step)/bias-corr) / cs.
__global__ void new_emb(const float* __restrict__ dw, const float* __restrict__ dwh,
                        const float* __restrict__ csv, float* __restrict__ out) {
    int kd = blockIdx.x * 256 + threadIdx.x;
    const float DECF = (float)(1.0 - 0.99);
    float e = dwh[kd];
    float hid = e - (e - dw[kd]) * DECF;
    float a = hid / DECF;
    out[O_NE + kd] = a / csv[kd >> 7];
}

extern "C" void kernel_launch(void* const* d_in, const int* in_sizes, int n_in,
                              void* d_out, int out_size, void* d_ws, size_t ws_size,
                              hipStream_t stream) {
    const float* x   = (const float*)d_in[0];
    const float* emb = (const float*)d_in[1];
    const float* dwh = (const float*)d_in[2];   // ema_dw_hidden
    const float* ch  = (const float*)d_in[3];   // ema_cluster_hidden
    float* out = (float*)d_out;
    float* ws  = (float*)d_ws;

    float* ET   = ws + WS_ET;
    float* ssx  = ws + WS_SSX;
    float* sse  = ws + WS_SSE;
    float* dw   = ws + WS_DW;
    float* csv  = ws + WS_CS;
    int*   counts = (int*)(ws + WS_CNT);
    int*   idxi   = (int*)(ws + WS_IDX);
    float* loss   = ws + WS_LOSS;

    hipMemsetAsync(dw, 0, NK * ND * sizeof(float), stream);
    hipMemsetAsync(counts, 0, NK * sizeof(int), stream);
    hipMemsetAsync(loss, 0, sizeof(float), stream);

    prep_e      <<<64,   256, 0, stream>>>(emb, ET, sse);
    calc_ssx    <<<512,  256, 0, stream>>>(x, ssx);
    gemm_argmin <<<1024, 256, 0, stream>>>(x, ET, ssx, sse, out, idxi, counts, loss);
    scatter_out_dw<<<512,256, 0, stream>>>(x, ET, idxi, out, dw);
    cs_loss     <<<1,    256, 0, stream>>>(counts, ch, loss, csv, out);
    new_emb     <<<512,  256, 0, stream>>>(dw, dwh, csv, out);
}

// Round 2
// 688.313 us; speedup vs baseline: 2.2513x; 2.2513x over previous
//
#include <hip/hip_runtime.h>

#define NB 64
#define ND 128
#define NT 2048
#define NK 1024
#define NN (NB*NT)            // 131072
#define DTSTRIDE (ND*NT)      // 262144, b-stride in x

// ---- workspace layout (float index) ----
#define WS_ET    0            // 131072 floats, ET[d][k] transposed embeddings
#define WS_SSX   131072       // 131072 floats, |x_n|^2
#define WS_SSE   262144       // 1024 floats,  |e_k|^2
#define WS_DW    263168       // 131072 floats, dw[k][d]
#define WS_CS    394240       // 1024 floats, laplace-smoothed cluster size
#define WS_CNT   395264       // 1024 ints, counts
#define WS_IDX   396288       // 131072 ints, argmin indices
#define WS_LOSS  527360       // 1 float, sum of best distances
#define WS_OFFS  527364       // 1024 ints, bucket offsets (exclusive scan)
#define WS_CUR   528388       // 1024 ints, bucket cursors
#define WS_LIST  529412       // 131072 ints, row-ids bucketed by k
#define WS_XT    660736       // 16777216 floats, xt[n][d] (needs ~70 MB ws)

// ---- output layout (concatenated, all fp32) ----
#define O_OUT 0
#define O_LC  16777216
#define O_LV  16777217
#define O_IDX 16777218
#define O_NE  16908290        // O_IDX + 131072

// Kernel 1: transpose embeddings [K][D] -> ET [D][K], and |e_k|^2.
__global__ void prep_e(const float* __restrict__ emb, float* __restrict__ ET,
                       float* __restrict__ sse) {
    int tid = threadIdx.x;
    int k   = blockIdx.x * 16 + (tid >> 4);
    int l   = tid & 15;
    float ss = 0.f;
    #pragma unroll
    for (int it = 0; it < 2; ++it) {
        int d0 = l * 4 + it * 64;
        float4 v = *(const float4*)(emb + k * ND + d0);
        ET[(d0+0)*NK + k] = v.x;
        ET[(d0+1)*NK + k] = v.y;
        ET[(d0+2)*NK + k] = v.z;
        ET[(d0+3)*NK + k] = v.w;
        ss = fmaf(v.x, v.x, ss); ss = fmaf(v.y, v.y, ss);
        ss = fmaf(v.z, v.z, ss); ss = fmaf(v.w, v.w, ss);
    }
    for (int m = 1; m <= 8; m <<= 1) ss += __shfl_xor(ss, m);
    if (l == 0) sse[k] = ss;
}

// Kernel 2: |x_n|^2 — kept bit-identical to the passing run (argmin numerics).
__global__ void calc_ssx(const float* __restrict__ x, float* __restrict__ ssx) {
    int b = blockIdx.x >> 3;
    int t = ((blockIdx.x & 7) << 8) + threadIdx.x;
    const float* xp = x + b * DTSTRIDE + t;
    float ss = 0.f;
    #pragma unroll 8
    for (int d = 0; d < ND; ++d) { float v = xp[d * NT]; ss = fmaf(v, v, ss); }
    ssx[b * NT + t] = ss;
}

// Kernel 2b: transpose x[B][D][T] -> xt[N][D] via LDS tile (conflict-free pad 33).
__global__ void transpose_x(const float* __restrict__ x, float* __restrict__ xt) {
    __shared__ float tile[128][33];
    int tid = threadIdx.x;
    int b   = blockIdx.x >> 6;
    int t0  = (blockIdx.x & 63) << 5;     // 32-wide t chunk
    int tl  = tid & 31;
    int dg  = tid >> 5;
    const float* xp = x + b * DTSTRIDE + t0 + tl;
    #pragma unroll
    for (int p = 0; p < 16; ++p) {
        int d = p * 8 + dg;
        tile[d][tl] = xp[d * NT];
    }
    __syncthreads();
    float* xtp = xt + (size_t)(b * NT + t0) * ND;
    #pragma unroll
    for (int c = 0; c < 4; ++c) {
        int d = c * 32 + (tid & 31);
        #pragma unroll
        for (int p = 0; p < 4; ++p) {
            int tr = p * 8 + (tid >> 5);
            xtp[tr * ND + d] = tile[d][tr];
        }
    }
}

// Kernel 3: fused distance GEMM + argmin + counts + loss-sum (unchanged).
__launch_bounds__(256, 2)
__global__ void gemm_argmin(const float* __restrict__ x, const float* __restrict__ ET,
                            const float* __restrict__ ssx, const float* __restrict__ sse,
                            float* __restrict__ out, int* __restrict__ idxi,
                            int* __restrict__ counts, float* __restrict__ loss) {
    __shared__ float xs[64][128];
    __shared__ float es[64][128];
    int tid = threadIdx.x;
    int blk = blockIdx.x;
    int b   = blk >> 4;
    int t0  = (blk & 15) << 7;
    int n0  = b * NT + t0;
    int tx  = tid & 15, ty = tid >> 4;
    int tx8 = tx * 8,   ty8 = ty * 8;
    int c4  = (tid & 31) * 4;
    int r0  = tid >> 5;

    float bestD[8]; int bestK[8]; float ssxv[8];
    #pragma unroll
    for (int i = 0; i < 8; ++i) {
        bestD[i] = 3.4e38f; bestK[i] = 0;
        ssxv[i]  = ssx[n0 + ty8 + i];
    }

    for (int kt = 0; kt < 8; ++kt) {
        float p[8][8];
        #pragma unroll
        for (int i = 0; i < 8; ++i)
            #pragma unroll
            for (int j = 0; j < 8; ++j) p[i][j] = 0.f;

        for (int dc = 0; dc < 2; ++dc) {
            __syncthreads();
            int d0 = dc * 64;
            #pragma unroll
            for (int r = 0; r < 8; ++r) {
                int dd = r0 + r * 8;
                *(float4*)(&xs[dd][c4]) = *(const float4*)(x  + b*DTSTRIDE + (d0+dd)*NT + t0 + c4);
                *(float4*)(&es[dd][c4]) = *(const float4*)(ET + (d0+dd)*NK + (kt<<7) + c4);
            }
            __syncthreads();
            #pragma unroll 2
            for (int dd = 0; dd < 64; ++dd) {
                float4 xa = *(float4*)&xs[dd][ty8];
                float4 xb = *(float4*)&xs[dd][ty8+4];
                float4 ea = *(float4*)&es[dd][tx8];
                float4 eb = *(float4*)&es[dd][tx8+4];
                float xr[8] = {xa.x,xa.y,xa.z,xa.w,xb.x,xb.y,xb.z,xb.w};
                float er[8] = {ea.x,ea.y,ea.z,ea.w,eb.x,eb.y,eb.z,eb.w};
                #pragma unroll
                for (int i = 0; i < 8; ++i)
                    #pragma unroll
                    for (int j = 0; j < 8; ++j)
                        p[i][j] = fmaf(xr[i], er[j], p[i][j]);
            }
        }
        #pragma unroll
        for (int j = 0; j < 8; ++j) {
            int   kidx = (kt << 7) + tx8 + j;
            float ssev = sse[kidx];
            #pragma unroll
            for (int i = 0; i < 8; ++i) {
                float t1   = ssxv[i] + ssev;
                float dist = fmaf(-2.f, p[i][j], t1);
                if (dist < bestD[i]) { bestD[i] = dist; bestK[i] = kidx; }
            }
        }
    }
    #pragma unroll
    for (int i = 0; i < 8; ++i) {
        float d = bestD[i]; int kk = bestK[i];
        for (int m = 1; m <= 8; m <<= 1) {
            float od = __shfl_xor(d, m);
            int   ok = __shfl_xor(kk, m);
            if (od < d || (od == d && ok < kk)) { d = od; kk = ok; }
        }
        bestD[i] = d; bestK[i] = kk;
    }
    if (tx == 0) {
        float ls = 0.f;
        #pragma unroll
        for (int i = 0; i < 8; ++i) {
            int n = n0 + ty8 + i;
            out[O_IDX + n] = (float)bestK[i];
            idxi[n] = bestK[i];
            atomicAdd(&counts[bestK[i]], 1);
            ls += bestD[i];
        }
        atomicAdd(loss, ls);
    }
}

// Kernel 4: straight-through output (no atomics).
__global__ void out_write(const float* __restrict__ x, const float* __restrict__ ET,
                          const int* __restrict__ idxi, float* __restrict__ out) {
    int b = blockIdx.x >> 3;
    int t = ((blockIdx.x & 7) << 8) + threadIdx.x;
    int k = idxi[b * NT + t];
    const float* xp = x + b * DTSTRIDE + t;
    float*       op = out + O_OUT + b * DTSTRIDE + t;
    #pragma unroll 4
    for (int d = 0; d < ND; ++d) {
        float xv = xp[d * NT];
        float q  = ET[d * NK + k];
        op[d * NT] = xv + (q - xv);
    }
}

// Kernel 5: exclusive scan of counts -> bucket offsets + cursors. One WG.
__global__ void scan_offs(const int* __restrict__ counts, int* __restrict__ offs,
                          int* __restrict__ cur) {
    __shared__ int s[256];
    int tid = threadIdx.x;
    int c[4]; int sum = 0;
    #pragma unroll
    for (int j = 0; j < 4; ++j) { c[j] = counts[tid*4+j]; sum += c[j]; }
    s[tid] = sum; __syncthreads();
    for (int off = 1; off < 256; off <<= 1) {
        int v = (tid >= off) ? s[tid - off] : 0;
        __syncthreads();
        s[tid] += v;
        __syncthreads();
    }
    int base = (tid == 0) ? 0 : s[tid-1];
    #pragma unroll
    for (int j = 0; j < 4; ++j) {
        offs[tid*4+j] = base; cur[tid*4+j] = base; base += c[j];
    }
}

// Kernel 6: bucket row-ids by k (int atomics on 1024 cursors only).
__global__ void fill_list(const int* __restrict__ idxi, int* __restrict__ cur,
                          int* __restrict__ list) {
    int n = blockIdx.x * 256 + threadIdx.x;
    int k = idxi[n];
    int pos = atomicAdd(&cur[k], 1);
    list[pos] = n;
}

// Kernel 7: dw[k][d] = sum of member rows. One WG per k, 2 rows in flight.
__global__ void dw_sum(const float* __restrict__ xt, const float* __restrict__ x,
                       const int* __restrict__ counts, const int* __restrict__ offs,
                       const int* __restrict__ list, float* __restrict__ dw,
                       int use_xt) {
    __shared__ float red[128];
    int k = blockIdx.x;
    int d = threadIdx.x & 127;
    int h = threadIdx.x >> 7;
    int cnt = counts[k], base = offs[k];
    float acc = 0.f;
    if (use_xt) {
        for (int m = h; m < cnt; m += 2) {
            int n = list[base + m];
            acc += xt[(size_t)n * ND + d];
        }
    } else {
        for (int m = h; m < cnt; m += 2) {
            int n = list[base + m];
            acc += x[(n >> 11) * DTSTRIDE + d * NT + (n & 2047)];
        }
    }
    if (h == 1) red[d] = acc;
    __syncthreads();
    if (h == 0) dw[k * ND + d] = acc + red[d];
}

// Kernel 8: cluster-size path (n, cs) + loss scalars. One WG.
__global__ void cs_loss(const int* __restrict__ counts, const float* __restrict__ ch,
                        const float* __restrict__ loss, float* __restrict__ csv,
                        float* __restrict__ out) {
    __shared__ float red[256];
    int tid = threadIdx.x;
    const float DECF = (float)(1.0 - 0.99);
    float s = 0.f;
    #pragma unroll
    for (int r = 0; r < 4; ++r) {
        int k = tid + r * 256;
        float c = (float)counts[k];
        float e = ch[k];
        float hid = e - (e - c) * DECF;
        s += hid / DECF;
    }
    red[tid] = s; __syncthreads();
    for (int off = 128; off > 0; off >>= 1) {
        if (tid < off) red[tid] += red[tid + off];
        __syncthreads();
    }
    float n = red[0];
    const float KEPSF = (float)(1024.0 * 1e-5);
    #pragma unroll
    for (int r = 0; r < 4; ++r) {
        int k = tid + r * 256;
        float c = (float)counts[k];
        float e = ch[k];
        float hid = e - (e - c) * DECF;
        float a = hid / DECF;
        csv[k] = (a + 1e-5f) / (n + KEPSF) * n;
    }
    if (tid == 0) {
        float mean = loss[0] / 16777216.f;
        out[O_LC] = 0.25f * mean;
        out[O_LV] = mean;
    }
}

// Kernel 9: new_embeddings.
__global__ void new_emb(const float* __restrict__ dw, const float* __restrict__ dwh,
                        const float* __restrict__ csv, float* __restrict__ out) {
    int kd = blockIdx.x * 256 + threadIdx.x;
    const float DECF = (float)(1.0 - 0.99);
    float e = dwh[kd];
    float hid = e - (e - dw[kd]) * DECF;
    float a = hid / DECF;
    out[O_NE + kd] = a / csv[kd >> 7];
}

extern "C" void kernel_launch(void* const* d_in, const int* in_sizes, int n_in,
                              void* d_out, int out_size, void* d_ws, size_t ws_size,
                              hipStream_t stream) {
    const float* x   = (const float*)d_in[0];
    const float* emb = (const float*)d_in[1];
    const float* dwh = (const float*)d_in[2];
    const float* ch  = (const float*)d_in[3];
    float* out = (float*)d_out;
    float* ws  = (float*)d_ws;

    float* ET   = ws + WS_ET;
    float* ssx  = ws + WS_SSX;
    float* sse  = ws + WS_SSE;
    float* dw   = ws + WS_DW;
    float* csv  = ws + WS_CS;
    int*   counts = (int*)(ws + WS_CNT);
    int*   idxi   = (int*)(ws + WS_IDX);
    float* loss   = ws + WS_LOSS;
    int*   offs   = (int*)(ws + WS_OFFS);
    int*   cur    = (int*)(ws + WS_CUR);
    int*   list   = (int*)(ws + WS_LIST);
    float* xt     = ws + WS_XT;

    int use_xt = (ws_size >= (size_t)(WS_XT + (size_t)NN * ND) * 4) ? 1 : 0;

    hipMemsetAsync(counts, 0, NK * sizeof(int), stream);
    hipMemsetAsync(loss, 0, sizeof(float), stream);

    prep_e      <<<64,   256, 0, stream>>>(emb, ET, sse);
    calc_ssx    <<<512,  256, 0, stream>>>(x, ssx);
    if (use_xt)
        transpose_x<<<4096, 256, 0, stream>>>(x, xt);
    gemm_argmin <<<1024, 256, 0, stream>>>(x, ET, ssx, sse, out, idxi, counts, loss);
    out_write   <<<512,  256, 0, stream>>>(x, ET, idxi, out);
    scan_offs   <<<1,    256, 0, stream>>>(counts, offs, cur);
    fill_list   <<<512,  256, 0, stream>>>(idxi, cur, list);
    dw_sum      <<<1024, 256, 0, stream>>>(xt, x, counts, offs, list, dw, use_xt);
    cs_loss     <<<1,    256, 0, stream>>>(counts, ch, loss, csv, out);
    new_emb     <<<512,  256, 0, stream>>>(dw, dwh, csv, out);
}

// Round 3
// 635.007 us; speedup vs baseline: 2.4403x; 1.0839x over previous
//
#include <hip/hip_runtime.h>

#define NB 64
#define ND 128
#define NT 2048
#define NK 1024
#define NN (NB*NT)            // 131072
#define DTSTRIDE (ND*NT)      // 262144, b-stride in x

typedef __attribute__((ext_vector_type(8))) short bf16x8;
typedef __attribute__((ext_vector_type(4))) float floatx4;

// ---- workspace layout (float index) ----
#define WS_ET    0            // 131072 floats, ET[d][k] fp32 (for out_write gather)
#define WS_SSX   131072       // 131072 floats, |x_n|^2
#define WS_SSE   262144       // 1024 floats,  |e_k|^2
#define WS_DW    263168       // 131072 floats, dw[k][d]
#define WS_CS    394240       // 1024 floats
#define WS_CNT   395264       // 1024 ints, counts
#define WS_IDX   396288       // 131072 ints, argmin indices
#define WS_LOSS  527360       // 1 float
#define WS_OFFS  527364       // 1024 ints
#define WS_CUR   528388       // 1024 ints
#define WS_LIST  529412       // 131072 ints
#define WS_XT    660736       // 16777216 floats, xt[n][d]
#define WS_EB    17437952     // 3 x 131072 ushorts (65536 floats each): bf16 e-planes
                              // layout per plane: [dchunk 4][k 1024][d 32]

// ---- output layout ----
#define O_OUT 0
#define O_LC  16777216
#define O_LV  16777217
#define O_IDX 16777218
#define O_NE  16908290

// exact truncation split of fp32 into 3 bf16 (bit patterns)
__device__ inline void split1(float v, unsigned short &a, unsigned short &b,
                              unsigned short &c) {
    unsigned int u = __float_as_uint(v);
    a = (unsigned short)(u >> 16);
    float f1 = __uint_as_float(u & 0xffff0000u);
    float r = v - f1;
    unsigned int ur = __float_as_uint(r);
    b = (unsigned short)(ur >> 16);
    float f2 = __uint_as_float(ur & 0xffff0000u);
    float r2 = r - f2;
    c = (unsigned short)(__float_as_uint(r2) >> 16);
}

// pack 2 consecutive elements into one uint per plane
__device__ inline void split2(float va, float vb, unsigned int &p1,
                              unsigned int &p2, unsigned int &p3) {
    unsigned int ua = __float_as_uint(va), ub = __float_as_uint(vb);
    p1 = (ua >> 16) | (ub & 0xffff0000u);
    float fa = __uint_as_float(ua & 0xffff0000u);
    float fb = __uint_as_float(ub & 0xffff0000u);
    float ra = va - fa, rb = vb - fb;
    unsigned int ura = __float_as_uint(ra), urb = __float_as_uint(rb);
    p2 = (ura >> 16) | (urb & 0xffff0000u);
    float f2a = __uint_as_float(ura & 0xffff0000u);
    float f2b = __uint_as_float(urb & 0xffff0000u);
    float r2a = ra - f2a, r2b = rb - f2b;
    p3 = (__float_as_uint(r2a) >> 16) | (__float_as_uint(r2b) & 0xffff0000u);
}

// Kernel 1: ET fp32 [d][k], sse (bit-identical to passing version), plus
// bf16 e-planes in [dchunk][k][32] blocked layout.
__global__ void prep_e(const float* __restrict__ emb, float* __restrict__ ET,
                       float* __restrict__ sse, unsigned short* __restrict__ eb1,
                       unsigned short* __restrict__ eb2, unsigned short* __restrict__ eb3) {
    int tid = threadIdx.x;
    int k   = blockIdx.x * 16 + (tid >> 4);
    int l   = tid & 15;
    float ss = 0.f;
    #pragma unroll
    for (int it = 0; it < 2; ++it) {
        int d0 = l * 4 + it * 64;
        float4 v = *(const float4*)(emb + k * ND + d0);
        ET[(d0+0)*NK + k] = v.x;
        ET[(d0+1)*NK + k] = v.y;
        ET[(d0+2)*NK + k] = v.z;
        ET[(d0+3)*NK + k] = v.w;
        ss = fmaf(v.x, v.x, ss); ss = fmaf(v.y, v.y, ss);
        ss = fmaf(v.z, v.z, ss); ss = fmaf(v.w, v.w, ss);
        // bf16 planes
        int dc  = (l >> 3) + it * 2;
        int off = (dc * NK + k) * 32 + (d0 & 31);
        ushort4 a, b, c;
        split1(v.x, a.x, b.x, c.x);
        split1(v.y, a.y, b.y, c.y);
        split1(v.z, a.z, b.z, c.z);
        split1(v.w, a.w, b.w, c.w);
        *(ushort4*)(eb1 + off) = a;
        *(ushort4*)(eb2 + off) = b;
        *(ushort4*)(eb3 + off) = c;
    }
    for (int m = 1; m <= 8; m <<= 1) ss += __shfl_xor(ss, m);
    if (l == 0) sse[k] = ss;
}

// Kernel 2: |x_n|^2 — unchanged (argmin-invariant anyway, but keep bits stable).
__global__ void calc_ssx(const float* __restrict__ x, float* __restrict__ ssx) {
    int b = blockIdx.x >> 3;
    int t = ((blockIdx.x & 7) << 8) + threadIdx.x;
    const float* xp = x + b * DTSTRIDE + t;
    float ss = 0.f;
    #pragma unroll 8
    for (int d = 0; d < ND; ++d) { float v = xp[d * NT]; ss = fmaf(v, v, ss); }
    ssx[b * NT + t] = ss;
}

// Kernel 2b: transpose x[B][D][T] -> xt[N][D] (unchanged).
__global__ void transpose_x(const float* __restrict__ x, float* __restrict__ xt) {
    __shared__ float tile[128][33];
    int tid = threadIdx.x;
    int b   = blockIdx.x >> 6;
    int t0  = (blockIdx.x & 63) << 5;
    int tl  = tid & 31;
    int dg  = tid >> 5;
    const float* xp = x + b * DTSTRIDE + t0 + tl;
    #pragma unroll
    for (int p = 0; p < 16; ++p) {
        int d = p * 8 + dg;
        tile[d][tl] = xp[d * NT];
    }
    __syncthreads();
    float* xtp = xt + (size_t)(b * NT + t0) * ND;
    #pragma unroll
    for (int c = 0; c < 4; ++c) {
        int d = c * 32 + (tid & 31);
        #pragma unroll
        for (int p = 0; p < 4; ++p) {
            int tr = p * 8 + (tid >> 5);
            xtp[tr * ND + d] = tile[d][tr];
        }
    }
}

// Kernel 3: MFMA distance GEMM + argmin + counts + loss.
// 1024 blocks, 4 waves; block = 128 rows x (8 kt-tiles of 128 codes), D in 4x32.
// p = sum of 6 bf16-split MFMA products (exact to ~2^-25 rel).
__launch_bounds__(256, 3)
__global__ void gemm_argmin_mfma(const float* __restrict__ xt,
                                 const unsigned short* __restrict__ eb1,
                                 const unsigned short* __restrict__ eb2,
                                 const unsigned short* __restrict__ eb3,
                                 const float* __restrict__ ssx, const float* __restrict__ sse,
                                 float* __restrict__ out, int* __restrict__ idxi,
                                 int* __restrict__ counts, float* __restrict__ loss) {
    // LDS: xs planes [3][128 rows][32 d] + es planes [3][128 codes][32 d], bf16,
    // 16B-block swizzled: block b of row r stored at slot b ^ ((r>>1)&3).
    __shared__ unsigned short smem[24576];   // 48 KB
    const int ES = 12288;

    int tid = threadIdx.x;
    int blk = blockIdx.x;
    int b   = blk >> 4;
    int t0  = (blk & 15) << 7;
    int n0  = b * NT + t0;

    int lane = tid & 63;
    int w    = tid >> 6;          // wave id, rows [w*32, w*32+32)
    int c    = lane & 15;
    int q    = lane >> 4;
    int slot = q ^ ((c >> 1) & 3);

    int r  = tid >> 1;            // staging row 0..127
    int h  = tid & 1;             // staging half (16 elements)
    int s0 = (2*h) ^ ((r >> 1) & 3);
    int s1 = s0 ^ 1;

    float ssxv[8];
    #pragma unroll
    for (int i = 0; i < 2; ++i)
        #pragma unroll
        for (int rr = 0; rr < 4; ++rr)
            ssxv[i*4+rr] = ssx[n0 + w*32 + i*16 + q*4 + rr];

    float bestD[8]; int bestK[8];
    #pragma unroll
    for (int i = 0; i < 8; ++i) { bestD[i] = 3.4e38f; bestK[i] = 0; }

    for (int kt = 0; kt < 8; ++kt) {
        floatx4 acc[2][8];
        #pragma unroll
        for (int i = 0; i < 2; ++i)
            #pragma unroll
            for (int j = 0; j < 8; ++j)
                acc[i][j] = (floatx4){0.f, 0.f, 0.f, 0.f};

        for (int dc = 0; dc < 4; ++dc) {
            __syncthreads();
            // --- stage es planes (bf16, pre-split, blocked layout) ---
            {
                int eoff = ((dc << 10) + (kt << 7) + r) * 32 + (h << 4);
                uint4 e0, e1;
                e0 = *(const uint4*)(eb1 + eoff); e1 = *(const uint4*)(eb1 + eoff + 8);
                *(uint4*)(&smem[ES + 0*4096 + r*32 + s0*8]) = e0;
                *(uint4*)(&smem[ES + 0*4096 + r*32 + s1*8]) = e1;
                e0 = *(const uint4*)(eb2 + eoff); e1 = *(const uint4*)(eb2 + eoff + 8);
                *(uint4*)(&smem[ES + 1*4096 + r*32 + s0*8]) = e0;
                *(uint4*)(&smem[ES + 1*4096 + r*32 + s1*8]) = e1;
                e0 = *(const uint4*)(eb3 + eoff); e1 = *(const uint4*)(eb3 + eoff + 8);
                *(uint4*)(&smem[ES + 2*4096 + r*32 + s0*8]) = e0;
                *(uint4*)(&smem[ES + 2*4096 + r*32 + s1*8]) = e1;
            }
            // --- stage xs planes: load fp32, split to 3 bf16 ---
            {
                const float* xp = xt + (size_t)(n0 + r) * ND + dc*32 + h*16;
                float4 v0 = *(const float4*)(xp + 0);
                float4 v1 = *(const float4*)(xp + 4);
                float4 v2 = *(const float4*)(xp + 8);
                float4 v3 = *(const float4*)(xp + 12);
                unsigned int p1[8], p2[8], p3[8];
                split2(v0.x, v0.y, p1[0], p2[0], p3[0]);
                split2(v0.z, v0.w, p1[1], p2[1], p3[1]);
                split2(v1.x, v1.y, p1[2], p2[2], p3[2]);
                split2(v1.z, v1.w, p1[3], p2[3], p3[3]);
                split2(v2.x, v2.y, p1[4], p2[4], p3[4]);
                split2(v2.z, v2.w, p1[5], p2[5], p3[5]);
                split2(v3.x, v3.y, p1[6], p2[6], p3[6]);
                split2(v3.z, v3.w, p1[7], p2[7], p3[7]);
                *(uint4*)(&smem[0*4096 + r*32 + s0*8]) = make_uint4(p1[0],p1[1],p1[2],p1[3]);
                *(uint4*)(&smem[0*4096 + r*32 + s1*8]) = make_uint4(p1[4],p1[5],p1[6],p1[7]);
                *(uint4*)(&smem[1*4096 + r*32 + s0*8]) = make_uint4(p2[0],p2[1],p2[2],p2[3]);
                *(uint4*)(&smem[1*4096 + r*32 + s1*8]) = make_uint4(p2[4],p2[5],p2[6],p2[7]);
                *(uint4*)(&smem[2*4096 + r*32 + s0*8]) = make_uint4(p3[0],p3[1],p3[2],p3[3]);
                *(uint4*)(&smem[2*4096 + r*32 + s1*8]) = make_uint4(p3[4],p3[5],p3[6],p3[7]);
            }
            __syncthreads();

            // --- A fragments: rows w*32 + i*16 + c, d = q*8..q*8+7 ---
            bf16x8 af[2][3];
            #pragma unroll
            for (int i = 0; i < 2; ++i)
                #pragma unroll
                for (int p = 0; p < 3; ++p)
                    af[i][p] = *(const bf16x8*)(&smem[p*4096 + (w*32 + i*16 + c)*32 + slot*8]);

            // --- MFMA over 8 code sub-tiles ---
            #pragma unroll
            for (int j = 0; j < 8; ++j) {
                bf16x8 b1 = *(const bf16x8*)(&smem[ES + 0*4096 + ((j<<4) + c)*32 + slot*8]);
                bf16x8 b2 = *(const bf16x8*)(&smem[ES + 1*4096 + ((j<<4) + c)*32 + slot*8]);
                bf16x8 b3 = *(const bf16x8*)(&smem[ES + 2*4096 + ((j<<4) + c)*32 + slot*8]);
                #pragma unroll
                for (int i = 0; i < 2; ++i) {
                    acc[i][j] = __builtin_amdgcn_mfma_f32_16x16x32_bf16(af[i][0], b1, acc[i][j], 0, 0, 0);
                    acc[i][j] = __builtin_amdgcn_mfma_f32_16x16x32_bf16(af[i][0], b2, acc[i][j], 0, 0, 0);
                    acc[i][j] = __builtin_amdgcn_mfma_f32_16x16x32_bf16(af[i][1], b1, acc[i][j], 0, 0, 0);
                    acc[i][j] = __builtin_amdgcn_mfma_f32_16x16x32_bf16(af[i][1], b2, acc[i][j], 0, 0, 0);
                    acc[i][j] = __builtin_amdgcn_mfma_f32_16x16x32_bf16(af[i][0], b3, acc[i][j], 0, 0, 0);
                    acc[i][j] = __builtin_amdgcn_mfma_f32_16x16x32_bf16(af[i][2], b1, acc[i][j], 0, 0, 0);
                }
            }
        }

        // --- epilogue for this kt tile: dist + argmin merge (k ascending) ---
        #pragma unroll
        for (int j = 0; j < 8; ++j) {
            int   kidx = (kt << 7) + (j << 4) + c;
            float ssev = sse[kidx];
            #pragma unroll
            for (int i = 0; i < 2; ++i) {
                #pragma unroll
                for (int rr = 0; rr < 4; ++rr) {
                    float t1   = ssxv[i*4+rr] + ssev;
                    float dist = fmaf(-2.f, acc[i][j][rr], t1);
                    if (dist < bestD[i*4+rr]) { bestD[i*4+rr] = dist; bestK[i*4+rr] = kidx; }
                }
            }
        }
    }

    // cross-lane argmin over the 16 c-lanes (ties -> smaller k)
    #pragma unroll
    for (int i = 0; i < 8; ++i) {
        float d = bestD[i]; int kk = bestK[i];
        for (int m = 1; m <= 8; m <<= 1) {
            float od = __shfl_xor(d, m);
            int   ok = __shfl_xor(kk, m);
            if (od < d || (od == d && ok < kk)) { d = od; kk = ok; }
        }
        bestD[i] = d; bestK[i] = kk;
    }
    if (c == 0) {
        float ls = 0.f;
        #pragma unroll
        for (int i = 0; i < 2; ++i)
            #pragma unroll
            for (int rr = 0; rr < 4; ++rr) {
                int n = n0 + w*32 + i*16 + q*4 + rr;
                int kk = bestK[i*4+rr];
                out[O_IDX + n] = (float)kk;
                idxi[n] = kk;
                atomicAdd(&counts[kk], 1);
                ls += bestD[i*4+rr];
            }
        atomicAdd(loss, ls);
    }
}

// Kernel 4: straight-through output (unchanged).
__global__ void out_write(const float* __restrict__ x, const float* __restrict__ ET,
                          const int* __restrict__ idxi, float* __restrict__ out) {
    int b = blockIdx.x >> 3;
    int t = ((blockIdx.x & 7) << 8) + threadIdx.x;
    int k = idxi[b * NT + t];
    const float* xp = x + b * DTSTRIDE + t;
    float*       op = out + O_OUT + b * DTSTRIDE + t;
    #pragma unroll 4
    for (int d = 0; d < ND; ++d) {
        float xv = xp[d * NT];
        float q  = ET[d * NK + k];
        op[d * NT] = xv + (q - xv);
    }
}

// Kernel 5: exclusive scan of counts (unchanged).
__global__ void scan_offs(const int* __restrict__ counts, int* __restrict__ offs,
                          int* __restrict__ cur) {
    __shared__ int s[256];
    int tid = threadIdx.x;
    int c[4]; int sum = 0;
    #pragma unroll
    for (int j = 0; j < 4; ++j) { c[j] = counts[tid*4+j]; sum += c[j]; }
    s[tid] = sum; __syncthreads();
    for (int off = 1; off < 256; off <<= 1) {
        int v = (tid >= off) ? s[tid - off] : 0;
        __syncthreads();
        s[tid] += v;
        __syncthreads();
    }
    int base = (tid == 0) ? 0 : s[tid-1];
    #pragma unroll
    for (int j = 0; j < 4; ++j) {
        offs[tid*4+j] = base; cur[tid*4+j] = base; base += c[j];
    }
}

// Kernel 6: bucket row-ids by k (unchanged).
__global__ void fill_list(const int* __restrict__ idxi, int* __restrict__ cur,
                          int* __restrict__ list) {
    int n = blockIdx.x * 256 + threadIdx.x;
    int k = idxi[n];
    int pos = atomicAdd(&cur[k], 1);
    list[pos] = n;
}

// Kernel 7: dw[k][d] via bucketed gather from xt (unchanged).
__global__ void dw_sum(const float* __restrict__ xt,
                       const int* __restrict__ counts, const int* __restrict__ offs,
                       const int* __restrict__ list, float* __restrict__ dw) {
    __shared__ float red[128];
    int k = blockIdx.x;
    int d = threadIdx.x & 127;
    int h = threadIdx.x >> 7;
    int cnt = counts[k], base = offs[k];
    float acc = 0.f;
    for (int m = h; m < cnt; m += 2) {
        int n = list[base + m];
        acc += xt[(size_t)n * ND + d];
    }
    if (h == 1) red[d] = acc;
    __syncthreads();
    if (h == 0) dw[k * ND + d] = acc + red[d];
}

// Kernel 8: cluster-size + losses (unchanged).
__global__ void cs_loss(const int* __restrict__ counts, const float* __restrict__ ch,
                        const float* __restrict__ loss, float* __restrict__ csv,
                        float* __restrict__ out) {
    __shared__ float red[256];
    int tid = threadIdx.x;
    const float DECF = (float)(1.0 - 0.99);
    float s = 0.f;
    #pragma unroll
    for (int rr = 0; rr < 4; ++rr) {
        int k = tid + rr * 256;
        float c = (float)counts[k];
        float e = ch[k];
        float hid = e - (e - c) * DECF;
        s += hid / DECF;
    }
    red[tid] = s; __syncthreads();
    for (int off = 128; off > 0; off >>= 1) {
        if (tid < off) red[tid] += red[tid + off];
        __syncthreads();
    }
    float n = red[0];
    const float KEPSF = (float)(1024.0 * 1e-5);
    #pragma unroll
    for (int rr = 0; rr < 4; ++rr) {
        int k = tid + rr * 256;
        float c = (float)counts[k];
        float e = ch[k];
        float hid = e - (e - c) * DECF;
        float a = hid / DECF;
        csv[k] = (a + 1e-5f) / (n + KEPSF) * n;
    }
    if (tid == 0) {
        float mean = loss[0] / 16777216.f;
        out[O_LC] = 0.25f * mean;
        out[O_LV] = mean;
    }
}

// Kernel 9: new_embeddings (unchanged).
__global__ void new_emb(const float* __restrict__ dw, const float* __restrict__ dwh,
                        const float* __restrict__ csv, float* __restrict__ out) {
    int kd = blockIdx.x * 256 + threadIdx.x;
    const float DECF = (float)(1.0 - 0.99);
    float e = dwh[kd];
    float hid = e - (e - dw[kd]) * DECF;
    float a = hid / DECF;
    out[O_NE + kd] = a / csv[kd >> 7];
}

extern "C" void kernel_launch(void* const* d_in, const int* in_sizes, int n_in,
                              void* d_out, int out_size, void* d_ws, size_t ws_size,
                              hipStream_t stream) {
    const float* x   = (const float*)d_in[0];
    const float* emb = (const float*)d_in[1];
    const float* dwh = (const float*)d_in[2];
    const float* ch  = (const float*)d_in[3];
    float* out = (float*)d_out;
    float* ws  = (float*)d_ws;

    float* ET   = ws + WS_ET;
    float* ssx  = ws + WS_SSX;
    float* sse  = ws + WS_SSE;
    float* dw   = ws + WS_DW;
    float* csv  = ws + WS_CS;
    int*   counts = (int*)(ws + WS_CNT);
    int*   idxi   = (int*)(ws + WS_IDX);
    float* loss   = ws + WS_LOSS;
    int*   offs   = (int*)(ws + WS_OFFS);
    int*   cur    = (int*)(ws + WS_CUR);
    int*   list   = (int*)(ws + WS_LIST);
    float* xt     = ws + WS_XT;
    unsigned short* eb1 = (unsigned short*)(ws + WS_EB);
    unsigned short* eb2 = eb1 + NK * ND;
    unsigned short* eb3 = eb2 + NK * ND;

    hipMemsetAsync(counts, 0, NK * sizeof(int), stream);
    hipMemsetAsync(loss, 0, sizeof(float), stream);

    prep_e         <<<64,   256, 0, stream>>>(emb, ET, sse, eb1, eb2, eb3);
    calc_ssx       <<<512,  256, 0, stream>>>(x, ssx);
    transpose_x    <<<4096, 256, 0, stream>>>(x, xt);
    gemm_argmin_mfma<<<1024,256, 0, stream>>>(xt, eb1, eb2, eb3, ssx, sse, out, idxi, counts, loss);
    out_write      <<<512,  256, 0, stream>>>(x, ET, idxi, out);
    scan_offs      <<<1,    256, 0, stream>>>(counts, offs, cur);
    fill_list      <<<512,  256, 0, stream>>>(idxi, cur, list);
    dw_sum         <<<1024, 256, 0, stream>>>(xt, counts, offs, list, dw);
    cs_loss        <<<1,    256, 0, stream>>>(counts, ch, loss, csv, out);
    new_emb        <<<512,  256, 0, stream>>>(dw, dwh, csv, out);
}